// Round 1
// baseline (526.853 us; speedup 1.0000x reference)
//
#include <hip/hip_runtime.h>
#include <cstdint>
#include <cstddef>

#define BB 8
#define LL 2048
#define DD 1024
#define KT 8   // number of 256-wide k tiles

typedef _Float16 f16;
typedef _Float16 f16x4 __attribute__((ext_vector_type(4)));
typedef _Float16 f16x8 __attribute__((ext_vector_type(8)));
typedef float f32x4 __attribute__((ext_vector_type(4)));

// async global->LDS, 16B per lane; LDS dest = wave-uniform base + lane*16
__device__ __forceinline__ void gload_lds16(const void* g, void* l) {
  __builtin_amdgcn_global_load_lds(
      (const __attribute__((address_space(1))) void*)g,
      (__attribute__((address_space(3))) void*)l, 16, 0, 0);
}

// ---------------- convert fp32 -> fp16 ----------------
__global__ void cvt_kernel(const float* __restrict__ src, f16* __restrict__ dst, int n) {
  const int t = blockIdx.x * blockDim.x + threadIdx.x;
  const int stride = gridDim.x * blockDim.x;
  for (int i = t * 4; i < n; i += stride * 4) {
    const float4 v = *(const float4*)(src + i);
    f16x4 o;
    o[0] = (f16)v.x; o[1] = (f16)v.y; o[2] = (f16)v.z; o[3] = (f16)v.w;
    *(f16x4*)(dst + i) = o;
  }
}

// ---------------- v (B,L,D) fp32 -> V16T (B,D,L) fp16 ----------------
__global__ void vtrans_kernel(const float* __restrict__ v, f16* __restrict__ vt) {
  __shared__ float tile[32][33];
  const int b = blockIdx.z;
  const int k0 = blockIdx.x * 32, d0 = blockIdx.y * 32;
  const int tx = threadIdx.x & 31, ty0 = threadIdx.x >> 5;
#pragma unroll
  for (int i = 0; i < 4; ++i) {
    int ty = ty0 + i * 8;
    tile[ty][tx] = v[((size_t)b * LL + k0 + ty) * DD + d0 + tx];
  }
  __syncthreads();
#pragma unroll
  for (int i = 0; i < 4; ++i) {
    int ty = ty0 + i * 8;
    vt[((size_t)b * DD + d0 + ty) * LL + k0 + tx] = (f16)tile[tx][ty];
  }
}

// ---------------- QK^T GEMM; MODE 0: per-tile (max,sum) partials; MODE 1: write P16
template <int MODE>
__global__ __launch_bounds__(256, 2) void qk_kernel(
    const f16* __restrict__ Q16, const f16* __restrict__ K16,
    const int* __restrict__ rep, float* __restrict__ part,
    const float* __restrict__ MR, f16* __restrict__ P16) {
  __shared__ __align__(16) f16 Qs[64 * 32];
  __shared__ __align__(16) f16 Ks[256 * 32];
  __shared__ float mrow[64];
  __shared__ float mcol[256];
  __shared__ float MRs[128];
  __shared__ float pm[256];
  __shared__ float pz[256];

  const int kt = blockIdx.x, qt = blockIdx.y, b = blockIdx.z;
  const int q0 = qt * 64, k0 = kt * 256;
  const int tid = threadIdx.x;
  const int w = tid >> 6, l = tid & 63;

  mcol[tid] = (float)rep[(size_t)b * LL + k0 + tid];
  if (tid < 64) mrow[tid] = (float)rep[(size_t)b * LL + q0 + tid];
  if (MODE == 1 && tid < 128) MRs[tid] = MR[((size_t)b * LL + q0) * 2 + tid];

  const int rl = l >> 2, jc = l & 3;
  const int jsrc = jc ^ ((rl >> 1) & 3);  // source-chunk pre-swizzle (T2-style, rule 21)
  const f16* qsrc = Q16 + ((size_t)b * LL + q0 + w * 16 + rl) * DD + jsrc * 8;
  const f16* ksrc = K16 + ((size_t)b * LL + k0 + w * 64 + rl) * DD + jsrc * 8;

  f32x4 acc[4][4] = {};
  const int lo16 = l & 15, hi = l >> 4;

  for (int ds = 0; ds < 32; ++ds) {
    gload_lds16(qsrc + ds * 32, &Qs[w * 16 * 32]);
    gload_lds16(ksrc + ds * 32,            &Ks[(w * 64) * 32]);
    gload_lds16(ksrc + 16 * DD + ds * 32,  &Ks[(w * 64 + 16) * 32]);
    gload_lds16(ksrc + 32 * DD + ds * 32,  &Ks[(w * 64 + 32) * 32]);
    gload_lds16(ksrc + 48 * DD + ds * 32,  &Ks[(w * 64 + 48) * 32]);
    __syncthreads();
    f16x8 af[4];
#pragma unroll
    for (int qf = 0; qf < 4; ++qf) {
      int r = qf * 16 + lo16;
      af[qf] = *(const f16x8*)&Qs[r * 32 + ((hi ^ ((r >> 1) & 3)) << 3)];
    }
#pragma unroll
    for (int kf = 0; kf < 4; ++kf) {
      int rk = w * 64 + kf * 16 + lo16;
      f16x8 bf = *(const f16x8*)&Ks[rk * 32 + ((hi ^ ((rk >> 1) & 3)) << 3)];
#pragma unroll
      for (int qf = 0; qf < 4; ++qf)
        acc[qf][kf] = __builtin_amdgcn_mfma_f32_16x16x32_f16(af[qf], bf, acc[qf][kf], 0, 0, 0);
    }
    __syncthreads();
  }

  float mkv[4];
#pragma unroll
  for (int kf = 0; kf < 4; ++kf) mkv[kf] = mcol[w * 64 + kf * 16 + lo16];

  if (MODE == 0) {
#pragma unroll
    for (int qf = 0; qf < 4; ++qf) {
#pragma unroll
      for (int r = 0; r < 4; ++r) {
        const int row = qf * 16 + hi * 4 + r;
        const float mqv = mrow[row];
        // masked_vec (mask zeros included in the max, exactly as reference)
        float v0 = acc[qf][0][r] * mqv * mkv[0];
        float v1 = acc[qf][1][r] * mqv * mkv[1];
        float v2 = acc[qf][2][r] * mqv * mkv[2];
        float v3 = acc[qf][3][r] * mqv * mkv[3];
        float mx = fmaxf(fmaxf(v0, v1), fmaxf(v2, v3));
#pragma unroll
        for (int s = 1; s < 16; s <<= 1) mx = fmaxf(mx, __shfl_xor(mx, s, 64));
        float zz = 0.f;
        zz += (mqv * mkv[0] != 0.f) ? __expf(v0 - mx) : 0.f;
        zz += (mqv * mkv[1] != 0.f) ? __expf(v1 - mx) : 0.f;
        zz += (mqv * mkv[2] != 0.f) ? __expf(v2 - mx) : 0.f;
        zz += (mqv * mkv[3] != 0.f) ? __expf(v3 - mx) : 0.f;
#pragma unroll
        for (int s = 1; s < 16; s <<= 1) zz += __shfl_xor(zz, s, 64);
        if (lo16 == 0) { pm[w * 64 + row] = mx; pz[w * 64 + row] = zz; }
      }
    }
    __syncthreads();
    if (tid < 64) {
      float m0 = pm[tid], m1 = pm[64 + tid], m2 = pm[128 + tid], m3 = pm[192 + tid];
      float M4 = fmaxf(fmaxf(m0, m1), fmaxf(m2, m3));
      float Z4 = pz[tid] * __expf(m0 - M4) + pz[64 + tid] * __expf(m1 - M4) +
                 pz[128 + tid] * __expf(m2 - M4) + pz[192 + tid] * __expf(m3 - M4);
      size_t base = (((size_t)b * LL + q0 + tid) * KT + kt) * 2;
      part[base] = M4;
      part[base + 1] = Z4;
    }
  } else {
#pragma unroll
    for (int qf = 0; qf < 4; ++qf) {
#pragma unroll
      for (int r = 0; r < 4; ++r) {
        const int row = qf * 16 + hi * 4 + r;
        const float mqv = mrow[row];
        const float Mv = MRs[row * 2], Rv = MRs[row * 2 + 1];
#pragma unroll
        for (int kf = 0; kf < 4; ++kf) {
          float p = 0.f;
          if (mqv * mkv[kf] != 0.f) p = __expf(acc[qf][kf][r] - Mv) * Rv;
          P16[((size_t)b * LL + q0 + row) * LL + (k0 + w * 64 + kf * 16 + lo16)] = (f16)p;
        }
      }
    }
  }
}

// ---------------- combine partials -> (M, R) per row ----------------
__global__ void combine_kernel(const float* __restrict__ part, float* __restrict__ MR) {
  const int row = blockIdx.x * blockDim.x + threadIdx.x;  // 0..B*L-1 exact
  const float* p = part + (size_t)row * KT * 2;
  float M = p[0];
#pragma unroll
  for (int t = 1; t < KT; ++t) M = fmaxf(M, p[2 * t]);
  float Z = 0.f;
#pragma unroll
  for (int t = 0; t < KT; ++t) Z += p[2 * t + 1] * __expf(p[2 * t] - M);
  float Zf = Z + ((Z == 0.f) ? 1.f : 0.f) + 1e-20f;
  MR[(size_t)row * 2] = M;
  MR[(size_t)row * 2 + 1] = 1.f / Zf;
}

// ---------------- PV GEMM: out = P16 @ V ----------------
__global__ __launch_bounds__(256, 2) void pv_kernel(
    const f16* __restrict__ P16, const f16* __restrict__ V16T, float* __restrict__ out) {
  __shared__ __align__(16) f16 Ps[64 * 32];
  __shared__ __align__(16) f16 Vs[4][64 * 32];
  const int dt = blockIdx.x, qt = blockIdx.y, b = blockIdx.z;
  const int q0 = qt * 64, d0 = dt * 256;
  const int tid = threadIdx.x, w = tid >> 6, l = tid & 63;
  const int rl = l >> 2, jc = l & 3, jsrc = jc ^ ((rl >> 1) & 3);
  const int lo16 = l & 15, hi = l >> 4;

  const f16* psrc = P16 + ((size_t)b * LL + q0 + w * 16 + rl) * LL + jsrc * 8;
  const f16* vsrc = V16T + ((size_t)b * DD + d0 + w * 64 + rl) * LL + jsrc * 8;

  f32x4 acc[4][4] = {};

  for (int ks = 0; ks < 64; ++ks) {
    gload_lds16(psrc + ks * 32, &Ps[w * 16 * 32]);
    gload_lds16(vsrc + ks * 32,           &Vs[w][0]);
    gload_lds16(vsrc + 16 * LL + ks * 32, &Vs[w][16 * 32]);
    gload_lds16(vsrc + 32 * LL + ks * 32, &Vs[w][32 * 32]);
    gload_lds16(vsrc + 48 * LL + ks * 32, &Vs[w][48 * 32]);
    __syncthreads();
    f16x8 af[4];
#pragma unroll
    for (int qf = 0; qf < 4; ++qf) {
      int r = qf * 16 + lo16;
      af[qf] = *(const f16x8*)&Ps[r * 32 + ((hi ^ ((r >> 1) & 3)) << 3)];
    }
#pragma unroll
    for (int df = 0; df < 4; ++df) {
      int rv = df * 16 + lo16;
      f16x8 bf = *(const f16x8*)&Vs[w][rv * 32 + ((hi ^ ((rv >> 1) & 3)) << 3)];
#pragma unroll
      for (int qf = 0; qf < 4; ++qf)
        acc[qf][df] = __builtin_amdgcn_mfma_f32_16x16x32_f16(af[qf], bf, acc[qf][df], 0, 0, 0);
    }
    __syncthreads();
  }
#pragma unroll
  for (int qf = 0; qf < 4; ++qf)
#pragma unroll
    for (int df = 0; df < 4; ++df)
#pragma unroll
      for (int r = 0; r < 4; ++r) {
        int row = qf * 16 + hi * 4 + r;
        int col = d0 + w * 64 + df * 16 + lo16;
        out[((size_t)b * LL + q0 + row) * DD + col] = acc[qf][df][r];
      }
}

extern "C" void kernel_launch(void* const* d_in, const int* in_sizes, int n_in,
                              void* d_out, int out_size, void* d_ws, size_t ws_size,
                              hipStream_t stream) {
  const float* q = (const float*)d_in[0];
  const float* k = (const float*)d_in[1];
  const float* v = (const float*)d_in[2];
  const int* rep = (const int*)d_in[3];
  float* out = (float*)d_out;

  char* ws = (char*)d_ws;
  // ws layout (bytes): Q16 32M | K16 32M | V16T 32M | P16 64M | part 1M | MR 128K
  f16* Q16 = (f16*)(ws);
  f16* K16 = (f16*)(ws + 33554432);
  f16* V16T = (f16*)(ws + 67108864);
  f16* P16 = (f16*)(ws + 100663296);
  float* part = (float*)(ws + 167772160);
  float* MR = (float*)(ws + 168820736);
  // total required: 168,951,808 bytes (~161.1 MiB)

  const int n = BB * LL * DD;
  cvt_kernel<<<2048, 256, 0, stream>>>(q, Q16, n);
  cvt_kernel<<<2048, 256, 0, stream>>>(k, K16, n);
  vtrans_kernel<<<dim3(LL / 32, DD / 32, BB), 256, 0, stream>>>(v, V16T);
  qk_kernel<0><<<dim3(KT, LL / 64, BB), 256, 0, stream>>>(Q16, K16, rep, part, nullptr, nullptr);
  combine_kernel<<<BB * LL / 256, 256, 0, stream>>>(part, MR);
  qk_kernel<1><<<dim3(KT, LL / 64, BB), 256, 0, stream>>>(Q16, K16, rep, nullptr, MR, P16);
  pv_kernel<<<dim3(DD / 256, LL / 64, BB), 256, 0, stream>>>(P16, V16T, out);
}

// Round 3
// 476.830 us; speedup vs baseline: 1.1049x; 1.1049x over previous
//
#include <hip/hip_runtime.h>
#include <cstdint>
#include <cstddef>

#define BB 8
#define LL 2048
#define DD 1024
#define KT 8   // number of 256-wide k tiles

typedef _Float16 f16;
typedef _Float16 f16x4 __attribute__((ext_vector_type(4)));
typedef _Float16 f16x8 __attribute__((ext_vector_type(8)));
typedef float f32x4 __attribute__((ext_vector_type(4)));

// async global->LDS, 16B per lane; LDS dest = wave-uniform base + lane*16
__device__ __forceinline__ void gload_lds16(const void* g, void* l) {
  __builtin_amdgcn_global_load_lds(
      (const __attribute__((address_space(1))) void*)g,
      (__attribute__((address_space(3))) void*)l, 16, 0, 0);
}

// ---------------- convert fp32 -> fp16 ----------------
__global__ void cvt_kernel(const float* __restrict__ src, f16* __restrict__ dst, int n) {
  const int t = blockIdx.x * blockDim.x + threadIdx.x;
  const int stride = gridDim.x * blockDim.x;
  for (int i = t * 4; i < n; i += stride * 4) {
    const float4 v = *(const float4*)(src + i);
    f16x4 o;
    o[0] = (f16)v.x; o[1] = (f16)v.y; o[2] = (f16)v.z; o[3] = (f16)v.w;
    *(f16x4*)(dst + i) = o;
  }
}

// ---------------- v (B,L,D) fp32 -> V16T (B,D,L) fp16 ----------------
__global__ void vtrans_kernel(const float* __restrict__ v, f16* __restrict__ vt) {
  __shared__ float tile[32][33];
  const int b = blockIdx.z;
  const int k0 = blockIdx.x * 32, d0 = blockIdx.y * 32;
  const int tx = threadIdx.x & 31, ty0 = threadIdx.x >> 5;
#pragma unroll
  for (int i = 0; i < 4; ++i) {
    int ty = ty0 + i * 8;
    tile[ty][tx] = v[((size_t)b * LL + k0 + ty) * DD + d0 + tx];
  }
  __syncthreads();
#pragma unroll
  for (int i = 0; i < 4; ++i) {
    int ty = ty0 + i * 8;
    vt[((size_t)b * DD + d0 + ty) * LL + k0 + tx] = (f16)tile[tx][ty];
  }
}

// ---------------- QK^T GEMM: per-TILE (max,sum) partials + TILE-normalized P~16
__global__ __launch_bounds__(256, 2) void qk_kernel(
    const f16* __restrict__ Q16, const f16* __restrict__ K16,
    const int* __restrict__ rep, float* __restrict__ part,
    f16* __restrict__ P16) {
  __shared__ __align__(16) f16 Qs[2][64 * 32];
  __shared__ __align__(16) f16 Ks[2][256 * 32];
  __shared__ float mrow[64];
  __shared__ float mcol[256];
  __shared__ float pm[256];
  __shared__ float pz[256];
  __shared__ float mr64[64];  // tile-level row max (256 cols)

  const int kt = blockIdx.x, qt = blockIdx.y, b = blockIdx.z;
  const int q0 = qt * 64, k0 = kt * 256;
  const int tid = threadIdx.x;
  const int w = tid >> 6, l = tid & 63;

  mcol[tid] = (float)rep[(size_t)b * LL + k0 + tid];
  if (tid < 64) mrow[tid] = (float)rep[(size_t)b * LL + q0 + tid];

  const int rl = l >> 2, jc = l & 3;
  const int jsrc = jc ^ ((rl >> 1) & 3);  // source-chunk pre-swizzle (rule 21)
  const f16* qsrc = Q16 + ((size_t)b * LL + q0 + w * 16 + rl) * DD + jsrc * 8;
  const f16* ksrc = K16 + ((size_t)b * LL + k0 + w * 64 + rl) * DD + jsrc * 8;

  f32x4 acc[4][4] = {};
  const int lo16 = l & 15, hi = l >> 4;

  auto stage = [&](int buf, int ds) {
    gload_lds16(qsrc + ds * 32, &Qs[buf][w * 16 * 32]);
    gload_lds16(ksrc + ds * 32,           &Ks[buf][(w * 64) * 32]);
    gload_lds16(ksrc + 16 * DD + ds * 32, &Ks[buf][(w * 64 + 16) * 32]);
    gload_lds16(ksrc + 32 * DD + ds * 32, &Ks[buf][(w * 64 + 32) * 32]);
    gload_lds16(ksrc + 48 * DD + ds * 32, &Ks[buf][(w * 64 + 48) * 32]);
  };

  stage(0, 0);
  __syncthreads();
  int cur = 0;
  for (int ds = 0; ds < 32; ++ds) {
    if (ds < 31) stage(cur ^ 1, ds + 1);  // prefetch next tile into other buffer
    f16x8 af[4];
#pragma unroll
    for (int qf = 0; qf < 4; ++qf) {
      int r = qf * 16 + lo16;
      af[qf] = *(const f16x8*)&Qs[cur][r * 32 + ((hi ^ ((r >> 1) & 3)) << 3)];
    }
#pragma unroll
    for (int kf = 0; kf < 4; ++kf) {
      int rk = w * 64 + kf * 16 + lo16;
      f16x8 bf = *(const f16x8*)&Ks[cur][rk * 32 + ((hi ^ ((rk >> 1) & 3)) << 3)];
#pragma unroll
      for (int qf = 0; qf < 4; ++qf)
        acc[qf][kf] = __builtin_amdgcn_mfma_f32_16x16x32_f16(af[qf], bf, acc[qf][kf], 0, 0, 0);
    }
    __syncthreads();  // drains vmcnt (prefetch) + lgkm; one barrier per K-step
    cur ^= 1;
  }

  float mkv[4];
#pragma unroll
  for (int kf = 0; kf < 4; ++kf) mkv[kf] = mcol[w * 64 + kf * 16 + lo16];

  // ---- pass 1: per-wave (64-col chunk) row maxes ----
#pragma unroll
  for (int qf = 0; qf < 4; ++qf) {
#pragma unroll
    for (int r = 0; r < 4; ++r) {
      const int row = qf * 16 + hi * 4 + r;
      const float mqv = mrow[row];
      float v0 = acc[qf][0][r] * mqv * mkv[0];
      float v1 = acc[qf][1][r] * mqv * mkv[1];
      float v2 = acc[qf][2][r] * mqv * mkv[2];
      float v3 = acc[qf][3][r] * mqv * mkv[3];
      float mx = fmaxf(fmaxf(v0, v1), fmaxf(v2, v3));
#pragma unroll
      for (int s = 1; s < 16; s <<= 1) mx = fmaxf(mx, __shfl_xor(mx, s, 64));
      if (lo16 == 0) pm[w * 64 + row] = mx;
    }
  }
  __syncthreads();
  if (tid < 64)
    mr64[tid] = fmaxf(fmaxf(pm[tid], pm[64 + tid]), fmaxf(pm[128 + tid], pm[192 + tid]));
  __syncthreads();

  // ---- pass 2: P~ = exp(masked - M_tile) * mask (fp16-safe), sums vs M_tile ----
#pragma unroll
  for (int qf = 0; qf < 4; ++qf) {
#pragma unroll
    for (int r = 0; r < 4; ++r) {
      const int row = qf * 16 + hi * 4 + r;
      const float mqv = mrow[row];
      const float Mv = mr64[row];
      float v0 = acc[qf][0][r] * mqv * mkv[0];
      float v1 = acc[qf][1][r] * mqv * mkv[1];
      float v2 = acc[qf][2][r] * mqv * mkv[2];
      float v3 = acc[qf][3][r] * mqv * mkv[3];
      float e0 = (mqv * mkv[0] != 0.f) ? __expf(v0 - Mv) : 0.f;
      float e1 = (mqv * mkv[1] != 0.f) ? __expf(v1 - Mv) : 0.f;
      float e2 = (mqv * mkv[2] != 0.f) ? __expf(v2 - Mv) : 0.f;
      float e3 = (mqv * mkv[3] != 0.f) ? __expf(v3 - Mv) : 0.f;
      const size_t prow = ((size_t)b * LL + q0 + row) * LL + k0 + w * 64 + lo16;
      P16[prow] = (f16)e0;
      P16[prow + 16] = (f16)e1;
      P16[prow + 32] = (f16)e2;
      P16[prow + 48] = (f16)e3;
      float zz = e0 + e1 + e2 + e3;
#pragma unroll
      for (int s = 1; s < 16; s <<= 1) zz += __shfl_xor(zz, s, 64);
      if (lo16 == 0) pz[w * 64 + row] = zz;
    }
  }
  __syncthreads();
  if (tid < 64) {
    // all wave partials share M_tile now: plain sum
    float Z4 = pz[tid] + pz[64 + tid] + pz[128 + tid] + pz[192 + tid];
    size_t base = (((size_t)b * LL + q0 + tid) * KT + kt) * 2;
    part[base] = mr64[tid];
    part[base + 1] = Z4;
  }
}

// ---------------- combine partials -> (M, R) per row ----------------
__global__ void combine_kernel(const float* __restrict__ part, float* __restrict__ MR) {
  const int row = blockIdx.x * blockDim.x + threadIdx.x;  // 0..B*L-1 exact
  const float* p = part + (size_t)row * KT * 2;
  float M = p[0];
#pragma unroll
  for (int t = 1; t < KT; ++t) M = fmaxf(M, p[2 * t]);
  float Z = 0.f;
#pragma unroll
  for (int t = 0; t < KT; ++t) Z += p[2 * t + 1] * __expf(p[2 * t] - M);
  float Zf = Z + ((Z == 0.f) ? 1.f : 0.f) + 1e-20f;
  MR[(size_t)row * 2] = M;
  MR[(size_t)row * 2 + 1] = 1.f / Zf;
}

// ---------------- PV GEMM: out = (c_t * P~) @ V, per-tile correction on A-frag
__global__ __launch_bounds__(256, 2) void pv_kernel(
    const f16* __restrict__ P16, const f16* __restrict__ V16T,
    const float* __restrict__ part, const float* __restrict__ MR,
    float* __restrict__ out) {
  __shared__ __align__(16) f16 Ps[2][64 * 32];
  __shared__ __align__(16) f16 Vs[2][4 * 64 * 32];
  __shared__ float cS[64][9];  // c[row][ktile], padded

  const int dt = blockIdx.x, qt = blockIdx.y, b = blockIdx.z;
  const int q0 = qt * 64, d0 = dt * 256;
  const int tid = threadIdx.x, w = tid >> 6, l = tid & 63;
  const int rl = l >> 2, jc = l & 3, jsrc = jc ^ ((rl >> 1) & 3);
  const int lo16 = l & 15, hi = l >> 4;

  // c[row][t] = exp(M_t - M_global) / Z_global  (all known upfront)
  for (int i = tid; i < 512; i += 256) {
    const int r = i >> 3, t = i & 7;
    const size_t grow = (size_t)b * LL + q0 + r;
    const float Mt = part[(grow * KT + t) * 2];
    const float Mg = MR[grow * 2], Rg = MR[grow * 2 + 1];
    cS[r][t] = __expf(Mt - Mg) * Rg;
  }

  const f16* psrc = P16 + ((size_t)b * LL + q0 + w * 16 + rl) * LL + jsrc * 8;
  const f16* vsrc = V16T + ((size_t)b * DD + d0 + w * 64 + rl) * LL + jsrc * 8;

  auto stage = [&](int buf, int ks) {
    gload_lds16(psrc + ks * 32, &Ps[buf][w * 16 * 32]);
    gload_lds16(vsrc + ks * 32,           &Vs[buf][w * 64 * 32]);
    gload_lds16(vsrc + 16 * LL + ks * 32, &Vs[buf][(w * 64 + 16) * 32]);
    gload_lds16(vsrc + 32 * LL + ks * 32, &Vs[buf][(w * 64 + 32) * 32]);
    gload_lds16(vsrc + 48 * LL + ks * 32, &Vs[buf][(w * 64 + 48) * 32]);
  };

  f32x4 acc[4][4] = {};
  stage(0, 0);
  __syncthreads();  // also publishes cS
  int cur = 0;
  for (int kt2 = 0; kt2 < 8; ++kt2) {
    f16 ct[4];
#pragma unroll
    for (int qf = 0; qf < 4; ++qf) ct[qf] = (f16)cS[qf * 16 + lo16][kt2];
    for (int ki = 0; ki < 8; ++ki) {
      const int ks = kt2 * 8 + ki;
      if (ks < 63) stage(cur ^ 1, ks + 1);
      f16x8 af[4];
#pragma unroll
      for (int qf = 0; qf < 4; ++qf) {
        int r = qf * 16 + lo16;
        af[qf] = *(const f16x8*)&Ps[cur][r * 32 + ((hi ^ ((r >> 1) & 3)) << 3)];
        const f16 c = ct[qf];
        f16x8 cv = {c, c, c, c, c, c, c, c};
        af[qf] = af[qf] * cv;  // fold per-(row,tile) softmax correction into A-frag
      }
#pragma unroll
      for (int df = 0; df < 4; ++df) {
        int rv = w * 64 + df * 16 + lo16;
        f16x8 bf = *(const f16x8*)&Vs[cur][rv * 32 + ((hi ^ ((rv >> 1) & 3)) << 3)];
#pragma unroll
        for (int qf = 0; qf < 4; ++qf)
          acc[qf][df] = __builtin_amdgcn_mfma_f32_16x16x32_f16(af[qf], bf, acc[qf][df], 0, 0, 0);
      }
      __syncthreads();
      cur ^= 1;
    }
  }
#pragma unroll
  for (int qf = 0; qf < 4; ++qf)
#pragma unroll
    for (int df = 0; df < 4; ++df)
#pragma unroll
      for (int r = 0; r < 4; ++r) {
        int row = qf * 16 + hi * 4 + r;
        int col = d0 + w * 64 + df * 16 + lo16;
        out[((size_t)b * LL + q0 + row) * DD + col] = acc[qf][df][r];
      }
}

extern "C" void kernel_launch(void* const* d_in, const int* in_sizes, int n_in,
                              void* d_out, int out_size, void* d_ws, size_t ws_size,
                              hipStream_t stream) {
  const float* q = (const float*)d_in[0];
  const float* k = (const float*)d_in[1];
  const float* v = (const float*)d_in[2];
  const int* rep = (const int*)d_in[3];
  float* out = (float*)d_out;

  char* ws = (char*)d_ws;
  // ws layout (bytes): Q16 32M | K16 32M | V16T 32M | P16 64M | part 1M | MR 128K
  f16* Q16 = (f16*)(ws);
  f16* K16 = (f16*)(ws + 33554432);
  f16* V16T = (f16*)(ws + 67108864);
  f16* P16 = (f16*)(ws + 100663296);
  float* part = (float*)(ws + 167772160);
  float* MR = (float*)(ws + 168820736);
  // total required: 168,951,808 bytes (~161.1 MiB)

  const int n = BB * LL * DD;
  cvt_kernel<<<2048, 256, 0, stream>>>(q, Q16, n);
  cvt_kernel<<<2048, 256, 0, stream>>>(k, K16, n);
  vtrans_kernel<<<dim3(LL / 32, DD / 32, BB), 256, 0, stream>>>(v, V16T);
  qk_kernel<<<dim3(KT, LL / 64, BB), 256, 0, stream>>>(Q16, K16, rep, part, P16);
  combine_kernel<<<BB * LL / 256, 256, 0, stream>>>(part, MR);
  pv_kernel<<<dim3(DD / 256, LL / 64, BB), 256, 0, stream>>>(P16, V16T, part, MR, out);
}